// Round 9
// baseline (269.002 us; speedup 1.0000x reference)
//
#include <hip/hip_runtime.h>
#include <hip/hip_bf16.h>

#define LOOKBACK 96
#define HID 128
#define HORIZON 24
#define NLAYERS 3

typedef __attribute__((ext_vector_type(8))) short short8v;
typedef __attribute__((ext_vector_type(4))) float f32x4;

__device__ __forceinline__ float bf_lo(uint u) { return __uint_as_float(u << 16); }
__device__ __forceinline__ float bf_hi(uint u) { return __uint_as_float(u & 0xffff0000u); }
__device__ __forceinline__ ushort f2bf(float f) {
    __hip_bfloat16 h = __float2bfloat16(f);
    return *(ushort*)&h;
}

// ---------------------------------------------------------------------------
// CSR build (counts zeroed via hipMemsetAsync). Pad granularity 16.
// ---------------------------------------------------------------------------
__global__ void hist_k(const int* __restrict__ dst, int* __restrict__ counts, int E) {
    int e = blockIdx.x * blockDim.x + threadIdx.x;
    if (e < E) atomicAdd(&counts[dst[e]], 1);
}

// per-block (1024 nodes) sum of PADDED counts
__global__ __launch_bounds__(1024) void bsum_k(const int* __restrict__ counts,
                                               int* __restrict__ bsum, int n) {
    __shared__ int s[1024];
    int t = threadIdx.x;
    int i = blockIdx.x * 1024 + t;
    s[t] = (i < n) ? ((counts[i] + 15) & ~15) : 0;
    __syncthreads();
    for (int off = 512; off > 0; off >>= 1) {
        if (t < off) s[t] += s[t + off];
        __syncthreads();
    }
    if (t == 0) bsum[blockIdx.x] = s[0];
}

// local scan of padded counts; block base computed in-kernel from bsum (nb<=64).
// writes offsets[0..n] (offsets[n] = total), cursor, dinv.
__global__ __launch_bounds__(1024) void scan_local_k(const int* __restrict__ counts,
                                                     const int* __restrict__ bsum,
                                                     int* __restrict__ offsets,
                                                     int* __restrict__ cursor,
                                                     float* __restrict__ dinv,
                                                     int n, int nb) {
    __shared__ int s[1024];
    __shared__ int sb[64];
    __shared__ int base_s;
    int t = threadIdx.x;
    int i = blockIdx.x * 1024 + t;
    if (t < 64) sb[t] = (t < nb) ? bsum[t] : 0;
    int c = (i < n) ? counts[i] : 0;
    int pc = (c + 15) & ~15;
    s[t] = pc;
    __syncthreads();
    if (t == 0) {
        int b = 0;
        for (int j = 0; j < (int)blockIdx.x; ++j) b += sb[j];
        base_s = b;
    }
    for (int off = 1; off < 1024; off <<= 1) {
        int x = s[t];
        int y = (t >= off) ? s[t - off] : 0;
        __syncthreads();
        s[t] = x + y;
        __syncthreads();
    }
    if (i < n) {
        int o = base_s + s[t] - pc;   // exclusive
        offsets[i] = o;
        cursor[i] = o;
        dinv[i] = rsqrtf((float)c + 1.0f);
        if (i == n - 1) offsets[n] = o + pc;
    }
}

// scatter + pad fill + WoutT prep + zero-row init, one kernel.
// scatter writes [off, off+cnt); pads write [off+cnt, off+pc) -> disjoint.
__global__ void scatter_pad_k(const int* __restrict__ src, const int* __restrict__ dst,
                              int* __restrict__ cursor,
                              const int* __restrict__ counts, const int* __restrict__ offsets,
                              int* __restrict__ srcs,
                              const float* __restrict__ W_out, ushort* __restrict__ WoutT,
                              ushort* __restrict__ zrow, int n, int E) {
    int i = blockIdx.x * 256 + threadIdx.x;
    if (i < 3072) {                          // W_out [128][24] -> WoutT [32][128]
        int k = i / 24, cc = i % 24;
        WoutT[cc * 128 + k] = f2bf(W_out[i]);
    } else if (i < 4096) {
        WoutT[i] = 0;                        // rows 24..31
    }
    if (i < 64) ((uint*)zrow)[i] = 0;        // zero feature row for pad gathers
    if (i < n) {
        int c = counts[i];
        int pc = (c + 15) & ~15;
        int off = offsets[i];
        for (int j = c; j < pc; ++j) srcs[off + j] = n;
    }
    if (i < E) {
        int pos = atomicAdd(&cursor[dst[i]], 1);
        srcs[pos] = src[i];
    }
}

// ---------------------------------------------------------------------------
// fused aggregation (bf16 in/out, fp32 accumulate), zh pre-scaled by dinv.
// Edge lists padded to multiple of 16 (pads -> zero row n).
// out[i] = relu( dinv[i]*( zh[i] + Sum_e zh[src] ) + bias )
// one wave per node, 2 features per lane; 16 dependence-free gathers per batch.
// ---------------------------------------------------------------------------
__global__ __launch_bounds__(256) void agg_k(
    const ushort* __restrict__ zh, ushort* __restrict__ out,
    const float* __restrict__ dinv,
    const int* __restrict__ offsets, const int* __restrict__ srcs,
    const float* __restrict__ bias, int n)
{
    int node = (blockIdx.x * 256 + threadIdx.x) >> 6;
    if (node >= n) return;
    node = __builtin_amdgcn_readfirstlane(node);   // wave-uniform -> scalar loads
    int lane = threadIdx.x & 63;
    int c = lane * 2;

    int off = offsets[node];
    int pc = offsets[node + 1] - off;
    const int* ep = srcs + off;

    float di = dinv[node];
    uint sv = *(const uint*)&zh[(size_t)node * HID + c];
    float s0 = bf_lo(sv), s1 = bf_hi(sv);

    for (int i = 0; i < pc; i += 16) {
        uint u[16];
        #pragma unroll
        for (int j = 0; j < 16; ++j)
            u[j] = *(const uint*)&zh[(size_t)ep[i + j] * HID + c];
        #pragma unroll
        for (int j = 0; j < 16; ++j) {
            s0 += bf_lo(u[j]);
            s1 += bf_hi(u[j]);
        }
    }

    float2 bv = *(const float2*)&bias[c];
    float r0 = fmaxf(fmaf(di, s0, bv.x), 0.0f);
    float r1 = fmaxf(fmaf(di, s1, bv.y), 0.0f);
    uint pk = (uint)f2bf(r0) | ((uint)f2bf(r1) << 16);
    *(uint*)&out[(size_t)node * HID + c] = pk;
}

// ---------------------------------------------------------------------------
// MFMA GEMM: C_bf16[n][128] = op( A[n][K] @ B_f32[K][128] )
//   AF32: A is f32 (convert in-kernel); BIAS: +bias[col]; SCALE: *dinv[row]
// block: 256 threads = 4 waves; tile 64 rows x 128 cols
// B staged transposed bf16 in LDS; C staged via LDS for coalesced b128 stores
// ---------------------------------------------------------------------------
template <int K, bool AF32, bool BIAS, bool SCALE>
__global__ __launch_bounds__(256) void mfma_gemm_k(
    const void* __restrict__ Araw, const float* __restrict__ B,
    const float* __restrict__ bias, const float* __restrict__ dinv,
    ushort* __restrict__ C, int n)
{
    constexpr int KSTEPS = K / 32;
    __shared__ ushort Bt[128][136];   // B^T; reused as C-stage after MFMA

    const int tid = threadIdx.x;
    const int wid = tid >> 6;
    const int lane = tid & 63;
    const int brow = blockIdx.x * 64;

    // stage B transposed (f32 -> bf16): Bt[col][k] = B[k][col], float4 loads
    #pragma unroll
    for (int i = tid; i < K * 32; i += 256) {
        float4 v = ((const float4*)B)[i];
        int idx = 4 * i;
        int k = idx >> 7;
        int cc = idx & 127;
        Bt[cc][k] = f2bf(v.x);
        Bt[cc + 1][k] = f2bf(v.y);
        Bt[cc + 2][k] = f2bf(v.z);
        Bt[cc + 3][k] = f2bf(v.w);
    }
    __syncthreads();

    // A fragment: row = l&15 (+wave offset), k-chunk = (l>>4)*8
    const int arow = brow + wid * 16 + (lane & 15);
    const int rowc = (arow < n) ? arow : (n - 1);
    const int kb = (lane >> 4) * 8;

    f32x4 acc[8];
    #pragma unroll
    for (int j = 0; j < 8; ++j) acc[j] = (f32x4){0.f, 0.f, 0.f, 0.f};

    #pragma unroll
    for (int kt = 0; kt < KSTEPS; ++kt) {
        short8v a;
        if (AF32) {
            const float* ap = (const float*)Araw + (size_t)rowc * K + kt * 32 + kb;
            float4 f0 = *(const float4*)ap;
            float4 f1 = *(const float4*)(ap + 4);
            a[0] = (short)f2bf(f0.x); a[1] = (short)f2bf(f0.y);
            a[2] = (short)f2bf(f0.z); a[3] = (short)f2bf(f0.w);
            a[4] = (short)f2bf(f1.x); a[5] = (short)f2bf(f1.y);
            a[6] = (short)f2bf(f1.z); a[7] = (short)f2bf(f1.w);
        } else {
            a = *(const short8v*)((const ushort*)Araw + (size_t)rowc * K + kt * 32 + kb);
        }
        #pragma unroll
        for (int j = 0; j < 8; ++j) {
            short8v b = *(const short8v*)&Bt[j * 16 + (lane & 15)][kt * 32 + kb];
            acc[j] = __builtin_amdgcn_mfma_f32_16x16x32_bf16(a, b, acc[j], 0, 0, 0);
        }
    }

    // epilogue: stage C tile in LDS (reuse Bt), then coalesced b128 stores.
    const int r0l = wid * 16 + (lane >> 4) * 4;
    float dsc[4];
    if (SCALE) {
        #pragma unroll
        for (int r = 0; r < 4; ++r)
            dsc[r] = (brow + r0l + r < n) ? dinv[brow + r0l + r] : 0.0f;
    }
    __syncthreads();                      // all Bt reads complete
    ushort* Cs = &Bt[0][0];               // [64][136] view
    const int cl = lane & 15;
    #pragma unroll
    for (int j = 0; j < 8; ++j) {
        int col = j * 16 + cl;
        float bv = BIAS ? bias[col] : 0.0f;
        #pragma unroll
        for (int r = 0; r < 4; ++r) {
            float v = acc[j][r];
            if (SCALE) v *= dsc[r];
            if (BIAS) v += bv;
            Cs[(r0l + r) * 136 + col] = f2bf(v);
        }
    }
    __syncthreads();
    int lrow = tid >> 2;
    int seg = (tid & 3) * 32;
    int grow = brow + lrow;
    if (grow < n) {
        #pragma unroll
        for (int q = 0; q < 4; ++q) {
            short8v v = *(const short8v*)&Cs[lrow * 136 + seg + q * 8];
            *(short8v*)&C[(size_t)grow * HID + seg + q * 8] = v;
        }
    }
}

// ---------------------------------------------------------------------------
// output MFMA GEMM: out_f32[n][24] = A_bf16[n][128] @ WoutT^T + b ; fuses y copy
// WoutT bf16 [32][128] (rows 24..31 zero). tile 64 rows x 32 cols.
// ---------------------------------------------------------------------------
__global__ __launch_bounds__(256) void gemm_out_k(
    const ushort* __restrict__ A, const ushort* __restrict__ BT,
    const float* __restrict__ bias, const float* __restrict__ y,
    float* __restrict__ out, float* __restrict__ ycopy, int n)
{
    const int tid = threadIdx.x;
    const int wid = tid >> 6;
    const int lane = tid & 63;
    const int brow = blockIdx.x * 64;
    const int arow = brow + wid * 16 + (lane & 15);
    const int rowc = (arow < n) ? arow : (n - 1);
    const int kb = (lane >> 4) * 8;

    f32x4 acc[2];
    acc[0] = (f32x4){0.f, 0.f, 0.f, 0.f};
    acc[1] = (f32x4){0.f, 0.f, 0.f, 0.f};

    #pragma unroll
    for (int kt = 0; kt < 4; ++kt) {
        short8v a = *(const short8v*)(A + (size_t)rowc * HID + kt * 32 + kb);
        #pragma unroll
        for (int j = 0; j < 2; ++j) {
            short8v b = *(const short8v*)&BT[(size_t)(j * 16 + (lane & 15)) * HID + kt * 32 + kb];
            acc[j] = __builtin_amdgcn_mfma_f32_16x16x32_bf16(a, b, acc[j], 0, 0, 0);
        }
    }

    const int r0 = brow + wid * 16 + (lane >> 4) * 4;
    const int cl = lane & 15;
    #pragma unroll
    for (int j = 0; j < 2; ++j) {
        int col = j * 16 + cl;
        if (col < HORIZON) {
            float bv = bias[col];
            #pragma unroll
            for (int r = 0; r < 4; ++r) {
                int row = r0 + r;
                if (row < n) out[(size_t)row * HORIZON + col] = acc[j][r] + bv;
            }
        }
    }

    // fused y copy: this block's 64 rows = 384 float4s
    const float4* y4 = (const float4*)y;
    float4* o4 = (float4*)ycopy;
    const int lim = n * 6;          // n*24/4
    int base = blockIdx.x * 384;
    for (int t = tid; t < 384; t += 256) {
        int i = base + t;
        if (i < lim) o4[i] = y4[i];
    }
}

// ---------------------------------------------------------------------------
extern "C" void kernel_launch(void* const* d_in, const int* in_sizes, int n_in,
                              void* d_out, int out_size, void* d_ws, size_t ws_size,
                              hipStream_t stream) {
    const float* x     = (const float*)d_in[0];
    const float* y     = (const float*)d_in[1];
    const int*   ei    = (const int*)d_in[2];     // int64 in ref -> int32 on device
    const float* W_in  = (const float*)d_in[3];
    const float* b_in  = (const float*)d_in[4];
    const float* Ws    = (const float*)d_in[5];
    const float* bs    = (const float*)d_in[6];
    const float* W_out = (const float*)d_in[7];
    const float* b_out = (const float*)d_in[8];
    float* out = (float*)d_out;

    const int n = in_sizes[0] / LOOKBACK;
    const int E = in_sizes[2] / 2;
    const int* src = ei;
    const int* dst = ei + E;
    const int nb = (n + 1023) / 1024;

    // workspace layout
    char* p = (char*)d_ws;
    float*  dinv    = (float*)p;   p += (size_t)n * 4;
    int*    counts  = (int*)p;     p += (size_t)n * 4;
    int*    offsets = (int*)p;     p += (size_t)(n + 4) * 4;
    int*    cursor  = (int*)p;     p += (size_t)n * 4;
    int*    bsum    = (int*)p;     p += (size_t)1024 * 4;
    int*    srcs    = (int*)p;     p += (size_t)(E + 16 * (size_t)n) * 4;   // padded CSR
    ushort* WoutT   = (ushort*)p;  p += (size_t)32 * 128 * 2;
    ushort* bufA    = (ushort*)p;  p += (size_t)(n + 1) * HID * 2;
    ushort* bufB    = (ushort*)p;  p += (size_t)(n + 1) * HID * 2;

    const int B = 256;
    // ---- CSR build + prep (5 dispatches) ----
    hipMemsetAsync(counts, 0, (size_t)n * 4, stream);
    hist_k<<<(E + B - 1) / B, B, 0, stream>>>(dst, counts, E);
    bsum_k<<<nb, 1024, 0, stream>>>(counts, bsum, n);
    scan_local_k<<<nb, 1024, 0, stream>>>(counts, bsum, offsets, cursor, dinv, n, nb);
    {
        int mx = (E > n) ? E : n;
        scatter_pad_k<<<(mx + B - 1) / B, B, 0, stream>>>(
            src, dst, cursor, counts, offsets, srcs,
            W_out, WoutT, bufB + (size_t)n * HID, n, E);
    }

    // ---- network ----
    const int gemm_grid = (n + 63) / 64;
    mfma_gemm_k<LOOKBACK, true, true, false><<<gemm_grid, 256, 0, stream>>>(
        x, W_in, b_in, nullptr, bufA, n);

    const int agg_grid = (n * 64 + 255) / 256;
    for (int l = 0; l < NLAYERS; ++l) {
        mfma_gemm_k<HID, false, false, true><<<gemm_grid, 256, 0, stream>>>(
            bufA, Ws + (size_t)l * HID * HID, nullptr, dinv, bufB, n);
        agg_k<<<agg_grid, 256, 0, stream>>>(bufB, bufA, dinv, offsets,
                                            srcs, bs + (size_t)l * HID, n);
    }

    gemm_out_k<<<gemm_grid, 256, 0, stream>>>(bufA, WoutT, b_out, y,
                                              out, out + (size_t)n * HORIZON, n);
}